// Round 3
// baseline (3031.523 us; speedup 1.0000x reference)
//
#include <hip/hip_runtime.h>
#include <hip/hip_bf16.h>

// Decoder block: B=2, T=2048, E=1024, H=16, D=64
// Inputs/outputs are FP32 (per reference dtypes; the 0.125 = 2% x 6.25 threshold
// confirms no bf16 floor). Internals: bf16 MFMA with fp32 accumulate.
// R1/R2 NaN root cause: reading fp32 arrays as bf16 (low mantissa halves decode
// to NaN/Inf bf16 patterns with p~2^-8 per element).

#define TT 2048
#define EE 1024
#define NH 16
#define HD 64

using bf16x8 = __bf16 __attribute__((ext_vector_type(8)));
using bf16x4 = __bf16 __attribute__((ext_vector_type(4)));
using f32x4  = float __attribute__((ext_vector_type(4)));

// ---------------- LayerNorm: fp32 in -> bf16 out. One block per row of 1024. ----
__global__ __launch_bounds__(256) void ln_kernel(const float* __restrict__ x,
                                                 const float* __restrict__ g,
                                                 const float* __restrict__ bta,
                                                 __bf16* __restrict__ out) {
    int row = blockIdx.x;
    int tid = threadIdx.x;
    const float4 xv = *(const float4*)(x + (size_t)row * EE + tid * 4);
    float s  = xv.x + xv.y + xv.z + xv.w;
    float ss = xv.x*xv.x + xv.y*xv.y + xv.z*xv.z + xv.w*xv.w;
    __shared__ float rs[256], rss[256];
    rs[tid] = s; rss[tid] = ss;
    __syncthreads();
    for (int st = 128; st > 0; st >>= 1) {
        if (tid < st) { rs[tid] += rs[tid+st]; rss[tid] += rss[tid+st]; }
        __syncthreads();
    }
    float mean = rs[0] * (1.0f / EE);
    float var  = rss[0] * (1.0f / EE) - mean * mean;
    float rstd = rsqrtf(var + 1e-5f);
    const float4 gv = *(const float4*)(g + tid * 4);
    const float4 bv = *(const float4*)(bta + tid * 4);
    bf16x4 ov;
    ov[0] = (__bf16)((xv.x - mean) * rstd * gv.x + bv.x);
    ov[1] = (__bf16)((xv.y - mean) * rstd * gv.y + bv.y);
    ov[2] = (__bf16)((xv.z - mean) * rstd * gv.z + bv.z);
    ov[3] = (__bf16)((xv.w - mean) * rstd * gv.w + bv.w);
    *(bf16x4*)(out + (size_t)row * EE + tid * 4) = ov;
}

// ---------------- MFMA bf16 GEMM: C[M,N] = act(A_bf16[M,K] @ B_f32[K,N] + bias) --
// block = 256 thr (4 waves), tile 64x64, K-step 32. B staged fp32->bf16 in LDS.
// resid (fp32) may alias C when CT=float (same-thread same-index RMW).
template<bool GELU, bool RESID, typename CT>
__global__ __launch_bounds__(256) void gemm_kernel(const __bf16* __restrict__ A,
                                                   const float* __restrict__ B,
                                                   const float* __restrict__ bias,
                                                   const float* resid,
                                                   CT* C,
                                                   int M, int N, int K) {
    __shared__ __align__(16) __bf16 As[64][32];
    __shared__ __align__(16) __bf16 Bs[32][64];
    int tid  = threadIdx.x;
    int wave = tid >> 6, lane = tid & 63;
    int quad = lane >> 4, l16 = lane & 15;
    int m0 = blockIdx.y * 64;
    int n0 = blockIdx.x * 64;

    f32x4 acc[4] = {};

    int ar = tid >> 2, ac = (tid & 3) * 8;   // A stage: 64 rows x 32 cols
    int br = tid >> 3, bc = (tid & 7) * 8;   // B stage: 32 rows x 64 cols
    const __bf16* Aptr = A + (size_t)(m0 + ar) * K + ac;
    const float*  Bptr = B + (size_t)br * N + n0 + bc;

    for (int kb = 0; kb < K; kb += 32) {
        *(bf16x8*)(&As[ar][ac]) = *(const bf16x8*)(Aptr + kb);
        float4 b0 = *(const float4*)(Bptr + (size_t)kb * N);
        float4 b1 = *(const float4*)(Bptr + (size_t)kb * N + 4);
        bf16x8 bstage;
        bstage[0] = (__bf16)b0.x; bstage[1] = (__bf16)b0.y;
        bstage[2] = (__bf16)b0.z; bstage[3] = (__bf16)b0.w;
        bstage[4] = (__bf16)b1.x; bstage[5] = (__bf16)b1.y;
        bstage[6] = (__bf16)b1.z; bstage[7] = (__bf16)b1.w;
        *(bf16x8*)(&Bs[br][bc]) = bstage;
        __syncthreads();
        bf16x8 af = *(const bf16x8*)(&As[wave * 16 + l16][quad * 8]);
#pragma unroll
        for (int nt = 0; nt < 4; nt++) {
            bf16x8 bfr;
#pragma unroll
            for (int j = 0; j < 8; j++) bfr[j] = Bs[quad * 8 + j][nt * 16 + l16];
            acc[nt] = __builtin_amdgcn_mfma_f32_16x16x32_bf16(af, bfr, acc[nt], 0, 0, 0);
        }
        __syncthreads();
    }
#pragma unroll
    for (int nt = 0; nt < 4; nt++) {
        int c = n0 + nt * 16 + l16;
        float bv = bias[c];
#pragma unroll
        for (int r = 0; r < 4; r++) {
            int row = m0 + wave * 16 + quad * 4 + r;
            float v = acc[nt][r] + bv;
            if (GELU)  v = 0.5f * v * (1.0f + erff(v * 0.70710678118f));
            if (RESID) v += resid[(size_t)row * N + c];
            C[(size_t)row * N + c] = (CT)v;
        }
    }
}

// ---------------- Causal attention: one block per (b, h, q). qkv/out bf16. -------
// qkv layout: [B*T][3E]; Q at col h*64, K at 1024+h*64, V at 2048+h*64
__global__ __launch_bounds__(256) void attn_kernel(const __bf16* __restrict__ qkv,
                                                   __bf16* __restrict__ out) {
    int q = blockIdx.x, h = blockIdx.y, b = blockIdx.z;
    int tid = threadIdx.x;
    __shared__ float qv[HD];
    __shared__ float sc[TT];
    __shared__ float red[256];
    __shared__ float vred[4][HD];

    size_t base = (size_t)b * TT * (3 * EE);
    const __bf16* qp = qkv + base + (size_t)q * (3 * EE) + h * HD;
    if (tid < HD) qv[tid] = (float)qp[tid];
    __syncthreads();

    // phase 1: scores + max
    float lmax = -1e30f;
    for (int k = tid; k <= q; k += 256) {
        const __bf16* kp = qkv + base + (size_t)k * (3 * EE) + EE + h * HD;
        float dot = 0.0f;
#pragma unroll
        for (int d = 0; d < HD; d++) dot += qv[d] * (float)kp[d];
        dot *= 0.125f;  // 1/sqrt(64)
        sc[k] = dot;
        lmax = fmaxf(lmax, dot);
    }
    red[tid] = lmax;
    __syncthreads();
    for (int s = 128; s > 0; s >>= 1) {
        if (tid < s) red[tid] = fmaxf(red[tid], red[tid + s]);
        __syncthreads();
    }
    float m = red[0];
    __syncthreads();

    // phase 2: exp + sum
    float lsum = 0.0f;
    for (int k = tid; k <= q; k += 256) {
        float e = __expf(sc[k] - m);
        sc[k] = e;
        lsum += e;
    }
    red[tid] = lsum;
    __syncthreads();
    for (int s = 128; s > 0; s >>= 1) {
        if (tid < s) red[tid] += red[tid + s];
        __syncthreads();
    }
    float inv = 1.0f / red[0];

    // phase 3: P @ V
    int d = tid & 63, g = tid >> 6;
    const __bf16* vp = qkv + base + 2 * EE + h * HD + d;
    float acc = 0.0f;
    for (int k = g; k <= q; k += 4) acc += sc[k] * (float)vp[(size_t)k * (3 * EE)];
    vred[g][d] = acc;
    __syncthreads();
    if (tid < HD) {
        float o = (vred[0][tid] + vred[1][tid] + vred[2][tid] + vred[3][tid]) * inv;
        out[((size_t)b * TT + q) * EE + h * HD + tid] = (__bf16)o;
    }
}

extern "C" void kernel_launch(void* const* d_in, const int* in_sizes, int n_in,
                              void* d_out, int out_size, void* d_ws, size_t ws_size,
                              hipStream_t stream) {
    const float* x     = (const float*)d_in[0];
    const float* ln1g  = (const float*)d_in[1];
    const float* ln1b  = (const float*)d_in[2];
    const float* ln2g  = (const float*)d_in[3];
    const float* ln2b  = (const float*)d_in[4];
    const float* Wqkv  = (const float*)d_in[5];
    const float* bqkv  = (const float*)d_in[6];
    const float* Wo    = (const float*)d_in[7];
    const float* bo    = (const float*)d_in[8];
    const float* Wfc   = (const float*)d_in[9];
    const float* bfc   = (const float*)d_in[10];
    const float* Wproj = (const float*)d_in[11];
    const float* bproj = (const float*)d_in[12];
    float* out = (float*)d_out;

    const int M = 2 * TT;  // 4096 tokens

    // Workspace (bf16, 41.9 MB total), lifetime-aliased:
    //   regQ: 16.8M elems — qkv [4096x3072] then ff [4096x4096]
    //   regS:  4.2M elems — h1 -> atn -> h2  [4096x1024]
    //   x1 (fp32) lives in d_out [4096x1024]
    __bf16* regQ = (__bf16*)d_ws;
    __bf16* regS = regQ + (size_t)M * 4 * EE;
    __bf16* qkv = regQ;
    __bf16* ff  = regQ;
    __bf16* h1  = regS;
    __bf16* atn = regS;
    __bf16* h2  = regS;
    float*  x1  = out;

    // LN1: x (fp32) -> h1 (bf16)
    ln_kernel<<<M, 256, 0, stream>>>(x, ln1g, ln1b, h1);
    // QKV: [4096,1024] @ [1024,3072] -> qkv (bf16)
    gemm_kernel<false, false, __bf16><<<dim3(3 * EE / 64, M / 64), 256, 0, stream>>>(
        h1, Wqkv, bqkv, nullptr, qkv, M, 3 * EE, EE);
    // causal attention: qkv -> atn (bf16; h1 dead, aliases regS)
    attn_kernel<<<dim3(TT, NH, 2), 256, 0, stream>>>(qkv, atn);
    // O-proj + residual(x): -> x1 (fp32, in d_out)
    gemm_kernel<false, true, float><<<dim3(EE / 64, M / 64), 256, 0, stream>>>(
        atn, Wo, bo, x, x1, M, EE, EE);
    // LN2: x1 (fp32) -> h2 (bf16; atn dead)
    ln_kernel<<<M, 256, 0, stream>>>(x1, ln2g, ln2b, h2);
    // FC + GELU: [4096,1024] @ [1024,4096] -> ff (bf16; qkv dead)
    gemm_kernel<true, false, __bf16><<<dim3(4 * EE / 64, M / 64), 256, 0, stream>>>(
        h2, Wfc, bfc, nullptr, ff, M, 4 * EE, EE);
    // proj + residual(x1): -> out (fp32; resid==C same-index RMW, safe)
    gemm_kernel<false, true, float><<<dim3(EE / 64, M / 64), 256, 0, stream>>>(
        ff, Wproj, bproj, x1, out, M, EE, 4 * EE);
}

// Round 4
// 778.235 us; speedup vs baseline: 3.8954x; 3.8954x over previous
//
#include <hip/hip_runtime.h>
#include <hip/hip_bf16.h>

// Decoder block: B=2, T=2048, E=1024, H=16, D=64
// Inputs/outputs FP32; internals bf16 MFMA + fp32 accumulate.
// R4: scalar attention (2610us, MfmaUtil=0) replaced with MFMA flash attention.

#define TT 2048
#define EE 1024
#define NH 16
#define HD 64

using bf16x8 = __bf16 __attribute__((ext_vector_type(8)));
using bf16x4 = __bf16 __attribute__((ext_vector_type(4)));
using f32x4  = float __attribute__((ext_vector_type(4)));

// ---------------- LayerNorm: fp32 in -> bf16 out. One block per row of 1024. ----
__global__ __launch_bounds__(256) void ln_kernel(const float* __restrict__ x,
                                                 const float* __restrict__ g,
                                                 const float* __restrict__ bta,
                                                 __bf16* __restrict__ out) {
    int row = blockIdx.x;
    int tid = threadIdx.x;
    const float4 xv = *(const float4*)(x + (size_t)row * EE + tid * 4);
    float s  = xv.x + xv.y + xv.z + xv.w;
    float ss = xv.x*xv.x + xv.y*xv.y + xv.z*xv.z + xv.w*xv.w;
    __shared__ float rs[256], rss[256];
    rs[tid] = s; rss[tid] = ss;
    __syncthreads();
    for (int st = 128; st > 0; st >>= 1) {
        if (tid < st) { rs[tid] += rs[tid+st]; rss[tid] += rss[tid+st]; }
        __syncthreads();
    }
    float mean = rs[0] * (1.0f / EE);
    float var  = rss[0] * (1.0f / EE) - mean * mean;
    float rstd = rsqrtf(var + 1e-5f);
    const float4 gv = *(const float4*)(g + tid * 4);
    const float4 bv = *(const float4*)(bta + tid * 4);
    bf16x4 ov;
    ov[0] = (__bf16)((xv.x - mean) * rstd * gv.x + bv.x);
    ov[1] = (__bf16)((xv.y - mean) * rstd * gv.y + bv.y);
    ov[2] = (__bf16)((xv.z - mean) * rstd * gv.z + bv.z);
    ov[3] = (__bf16)((xv.w - mean) * rstd * gv.w + bv.w);
    *(bf16x4*)(out + (size_t)row * EE + tid * 4) = ov;
}

// ---------------- MFMA bf16 GEMM (unchanged from R3, verified) -------------------
template<bool GELU, bool RESID, typename CT>
__global__ __launch_bounds__(256) void gemm_kernel(const __bf16* __restrict__ A,
                                                   const float* __restrict__ B,
                                                   const float* __restrict__ bias,
                                                   const float* resid,
                                                   CT* C,
                                                   int M, int N, int K) {
    __shared__ __align__(16) __bf16 As[64][32];
    __shared__ __align__(16) __bf16 Bs[32][64];
    int tid  = threadIdx.x;
    int wave = tid >> 6, lane = tid & 63;
    int quad = lane >> 4, l16 = lane & 15;
    int m0 = blockIdx.y * 64;
    int n0 = blockIdx.x * 64;

    f32x4 acc[4] = {};

    int ar = tid >> 2, ac = (tid & 3) * 8;
    int br = tid >> 3, bc = (tid & 7) * 8;
    const __bf16* Aptr = A + (size_t)(m0 + ar) * K + ac;
    const float*  Bptr = B + (size_t)br * N + n0 + bc;

    for (int kb = 0; kb < K; kb += 32) {
        *(bf16x8*)(&As[ar][ac]) = *(const bf16x8*)(Aptr + kb);
        float4 b0 = *(const float4*)(Bptr + (size_t)kb * N);
        float4 b1 = *(const float4*)(Bptr + (size_t)kb * N + 4);
        bf16x8 bstage;
        bstage[0] = (__bf16)b0.x; bstage[1] = (__bf16)b0.y;
        bstage[2] = (__bf16)b0.z; bstage[3] = (__bf16)b0.w;
        bstage[4] = (__bf16)b1.x; bstage[5] = (__bf16)b1.y;
        bstage[6] = (__bf16)b1.z; bstage[7] = (__bf16)b1.w;
        *(bf16x8*)(&Bs[br][bc]) = bstage;
        __syncthreads();
        bf16x8 af = *(const bf16x8*)(&As[wave * 16 + l16][quad * 8]);
#pragma unroll
        for (int nt = 0; nt < 4; nt++) {
            bf16x8 bfr;
#pragma unroll
            for (int j = 0; j < 8; j++) bfr[j] = Bs[quad * 8 + j][nt * 16 + l16];
            acc[nt] = __builtin_amdgcn_mfma_f32_16x16x32_bf16(af, bfr, acc[nt], 0, 0, 0);
        }
        __syncthreads();
    }
#pragma unroll
    for (int nt = 0; nt < 4; nt++) {
        int c = n0 + nt * 16 + l16;
        float bv = bias[c];
#pragma unroll
        for (int r = 0; r < 4; r++) {
            int row = m0 + wave * 16 + quad * 4 + r;
            float v = acc[nt][r] + bv;
            if (GELU)  v = 0.5f * v * (1.0f + erff(v * 0.70710678118f));
            if (RESID) v += resid[(size_t)row * N + c];
            C[(size_t)row * N + c] = (CT)v;
        }
    }
}

// ---------------- MFMA flash attention -------------------------------------------
// One block (4 waves) per (b, h, 64-row Q-tile). Wave w owns Q rows [q0+16w, q0+16w+16).
// K-tile = 64 keys staged in LDS as Ks[key][d] and V^T as VTs[d][key] (pad 72).
// Online softmax in MFMA C-layout; P -> A-layout via per-wave LDS round-trip.
__global__ __launch_bounds__(256) void flash_attn_kernel(const __bf16* __restrict__ qkv,
                                                         __bf16* __restrict__ out) {
    int qt = (int)gridDim.x - 1 - (int)blockIdx.x;  // reversed: big tiles first
    int h = blockIdx.y, b = blockIdx.z;
    int tid = threadIdx.x, wave = tid >> 6, lane = tid & 63;
    int quad = lane >> 4, l16 = lane & 15;
    int q0 = qt * 64;

    __shared__ __align__(16) __bf16 Ks[64][72];   // [key][d]
    __shared__ __align__(16) __bf16 VTs[64][72];  // [d][key]
    __shared__ __align__(16) __bf16 Ps[4][16][72];// per-wave P round-trip

    size_t base = (size_t)b * TT * (3 * EE);

    // Q A-fragments straight from global: A[m=l16][k=quad*8+j], two k-halves of D=64
    int qrow = q0 + wave * 16 + l16;
    const __bf16* qp = qkv + base + (size_t)qrow * (3 * EE) + h * HD;
    bf16x8 aq0 = *(const bf16x8*)(qp + quad * 8);
    bf16x8 aq1 = *(const bf16x8*)(qp + 32 + quad * 8);

    f32x4 oacc[4] = {};
    float m_i[4], l_i[4];
#pragma unroll
    for (int r = 0; r < 4; r++) { m_i[r] = -3.0e38f; l_i[r] = 0.0f; }
    int qg_base = q0 + wave * 16 + quad * 4;  // C-layout row base for this lane

    for (int kt = 0; kt <= qt; ++kt) {
        int k0 = kt * 64;
        // ---- stage K tile and V^T tile (cooperative, 256 thr) ----
        int v = tid;
#pragma unroll
        for (int it = 0; it < 2; ++it, v += 256) {
            int row = v >> 3, col = (v & 7) * 8;
            const __bf16* kp = qkv + base + (size_t)(k0 + row) * (3 * EE) + EE + h * HD + col;
            const __bf16* vp = qkv + base + (size_t)(k0 + row) * (3 * EE) + 2 * EE + h * HD + col;
            *(bf16x8*)(&Ks[row][col]) = *(const bf16x8*)kp;
            bf16x8 vv = *(const bf16x8*)vp;
#pragma unroll
            for (int j = 0; j < 8; j++) VTs[col + j][row] = vv[j];
        }
        __syncthreads();

        // ---- S = Q K^T : 16 q-rows x 64 keys per wave ----
        f32x4 s[4] = {};
#pragma unroll
        for (int nt = 0; nt < 4; nt++) {
            bf16x8 bk0 = *(const bf16x8*)(&Ks[nt * 16 + l16][quad * 8]);
            bf16x8 bk1 = *(const bf16x8*)(&Ks[nt * 16 + l16][32 + quad * 8]);
            s[nt] = __builtin_amdgcn_mfma_f32_16x16x32_bf16(aq0, bk0, s[nt], 0, 0, 0);
            s[nt] = __builtin_amdgcn_mfma_f32_16x16x32_bf16(aq1, bk1, s[nt], 0, 0, 0);
        }

        // ---- scale + causal mask (diagonal tile only) + row max ----
        bool maskt = (kt == qt);
        float rmax[4];
#pragma unroll
        for (int r = 0; r < 4; r++) rmax[r] = -3.0e38f;
#pragma unroll
        for (int nt = 0; nt < 4; nt++) {
            int key = k0 + nt * 16 + l16;
#pragma unroll
            for (int r = 0; r < 4; r++) {
                float sv = s[nt][r] * 0.125f;
                if (maskt && key > qg_base + r) sv = -3.0e38f;
                s[nt][r] = sv;
                rmax[r] = fmaxf(rmax[r], sv);
            }
        }
#pragma unroll
        for (int off = 1; off < 16; off <<= 1)
#pragma unroll
            for (int r = 0; r < 4; r++) rmax[r] = fmaxf(rmax[r], __shfl_xor(rmax[r], off));

        // ---- online softmax update ----
        float alpha[4], rsum[4];
#pragma unroll
        for (int r = 0; r < 4; r++) {
            float mnew = fmaxf(m_i[r], rmax[r]);
            alpha[r] = __expf(m_i[r] - mnew);
            m_i[r] = mnew;
            rsum[r] = 0.0f;
        }
#pragma unroll
        for (int nt = 0; nt < 4; nt++) {
#pragma unroll
            for (int r = 0; r < 4; r++) {
                float p = __expf(s[nt][r] - m_i[r]);
                rsum[r] += p;
                Ps[wave][quad * 4 + r][nt * 16 + l16] = (__bf16)p;
            }
        }
#pragma unroll
        for (int off = 1; off < 16; off <<= 1)
#pragma unroll
            for (int r = 0; r < 4; r++) rsum[r] += __shfl_xor(rsum[r], off);
#pragma unroll
        for (int r = 0; r < 4; r++) {
            l_i[r] = l_i[r] * alpha[r] + rsum[r];
#pragma unroll
            for (int nt = 0; nt < 4; nt++) oacc[nt][r] *= alpha[r];
        }

        // ---- O += P V : P A-frags from per-wave LDS, V^T B-frags ----
#pragma unroll
        for (int half = 0; half < 2; half++) {
            bf16x8 ap = *(const bf16x8*)(&Ps[wave][l16][half * 32 + quad * 8]);
#pragma unroll
            for (int nt = 0; nt < 4; nt++) {
                bf16x8 bv = *(const bf16x8*)(&VTs[nt * 16 + l16][half * 32 + quad * 8]);
                oacc[nt] = __builtin_amdgcn_mfma_f32_16x16x32_bf16(ap, bv, oacc[nt], 0, 0, 0);
            }
        }
        __syncthreads();  // before next tile overwrites Ks/VTs
    }

    // ---- epilogue: O / l, write bf16 ----
#pragma unroll
    for (int nt = 0; nt < 4; nt++) {
#pragma unroll
        for (int r = 0; r < 4; r++) {
            int qg = qg_base + r;
            out[((size_t)b * TT + qg) * EE + h * HD + nt * 16 + l16] =
                (__bf16)(oacc[nt][r] / l_i[r]);
        }
    }
}

extern "C" void kernel_launch(void* const* d_in, const int* in_sizes, int n_in,
                              void* d_out, int out_size, void* d_ws, size_t ws_size,
                              hipStream_t stream) {
    const float* x     = (const float*)d_in[0];
    const float* ln1g  = (const float*)d_in[1];
    const float* ln1b  = (const float*)d_in[2];
    const float* ln2g  = (const float*)d_in[3];
    const float* ln2b  = (const float*)d_in[4];
    const float* Wqkv  = (const float*)d_in[5];
    const float* bqkv  = (const float*)d_in[6];
    const float* Wo    = (const float*)d_in[7];
    const float* bo    = (const float*)d_in[8];
    const float* Wfc   = (const float*)d_in[9];
    const float* bfc   = (const float*)d_in[10];
    const float* Wproj = (const float*)d_in[11];
    const float* bproj = (const float*)d_in[12];
    float* out = (float*)d_out;

    const int M = 2 * TT;  // 4096 tokens

    // Workspace (bf16, 41.9 MB), lifetime-aliased:
    //   regQ: qkv [4096x3072] then ff [4096x4096]
    //   regS: h1 -> atn -> h2 [4096x1024]
    //   x1 (fp32) lives in d_out
    __bf16* regQ = (__bf16*)d_ws;
    __bf16* regS = regQ + (size_t)M * 4 * EE;
    __bf16* qkv = regQ;
    __bf16* ff  = regQ;
    __bf16* h1  = regS;
    __bf16* atn = regS;
    __bf16* h2  = regS;
    float*  x1  = out;

    ln_kernel<<<M, 256, 0, stream>>>(x, ln1g, ln1b, h1);
    gemm_kernel<false, false, __bf16><<<dim3(3 * EE / 64, M / 64), 256, 0, stream>>>(
        h1, Wqkv, bqkv, nullptr, qkv, M, 3 * EE, EE);
    flash_attn_kernel<<<dim3(TT / 64, NH, 2), 256, 0, stream>>>(qkv, atn);
    gemm_kernel<false, true, float><<<dim3(EE / 64, M / 64), 256, 0, stream>>>(
        atn, Wo, bo, x, x1, M, EE, EE);
    ln_kernel<<<M, 256, 0, stream>>>(x1, ln2g, ln2b, h2);
    gemm_kernel<true, false, __bf16><<<dim3(4 * EE / 64, M / 64), 256, 0, stream>>>(
        h2, Wfc, bfc, nullptr, ff, M, 4 * EE, EE);
    gemm_kernel<false, true, float><<<dim3(EE / 64, M / 64), 256, 0, stream>>>(
        ff, Wproj, bproj, x1, out, M, EE, 4 * EE);
}

// Round 5
// 517.109 us; speedup vs baseline: 5.8624x; 1.5050x over previous
//
#include <hip/hip_runtime.h>
#include <hip/hip_bf16.h>

// Decoder block: B=2, T=2048, E=1024, H=16, D=64
// Inputs/outputs FP32; internals bf16 MFMA + fp32 accumulate.
// R5: weights pre-converted to bf16 [N][K] (transposed), GEMMs moved to the
// m97-verified structure: 128-tile, global_load_lds width=16, contiguous
// ds_read_b128 fragments. R4 GEMMs showed MfmaUtil 6.9% + 3.6e7 bank conflicts.

#define TT 2048
#define EE 1024
#define NH 16
#define HD 64

#define AS1 __attribute__((address_space(1)))
#define AS3 __attribute__((address_space(3)))

using bf16x8 = __bf16 __attribute__((ext_vector_type(8)));
using bf16x4 = __bf16 __attribute__((ext_vector_type(4)));
using f32x4  = float __attribute__((ext_vector_type(4)));

// ---------------- fp32 [K][N] -> bf16 [N][K] tiled transpose-convert ------------
__global__ __launch_bounds__(256) void convt_kernel(const float* __restrict__ W,
                                                    __bf16* __restrict__ WT,
                                                    int K, int N) {
    __shared__ __bf16 t[32][33];
    int n0 = blockIdx.x * 32, k0 = blockIdx.y * 32;
    int tid = threadIdx.x;
    int r = tid >> 3, c4 = (tid & 7) * 4;
    float4 v = *(const float4*)(W + (size_t)(k0 + r) * N + n0 + c4);
    t[r][c4 + 0] = (__bf16)v.x; t[r][c4 + 1] = (__bf16)v.y;
    t[r][c4 + 2] = (__bf16)v.z; t[r][c4 + 3] = (__bf16)v.w;
    __syncthreads();
    bf16x4 o;
    o[0] = t[c4 + 0][r]; o[1] = t[c4 + 1][r];
    o[2] = t[c4 + 2][r]; o[3] = t[c4 + 3][r];
    *(bf16x4*)(WT + (size_t)(n0 + r) * K + k0 + c4) = o;
}

// ---------------- LayerNorm: fp32 in -> bf16 out. One block per row of 1024. ----
__global__ __launch_bounds__(256) void ln_kernel(const float* __restrict__ x,
                                                 const float* __restrict__ g,
                                                 const float* __restrict__ bta,
                                                 __bf16* __restrict__ out) {
    int row = blockIdx.x;
    int tid = threadIdx.x;
    const float4 xv = *(const float4*)(x + (size_t)row * EE + tid * 4);
    float s  = xv.x + xv.y + xv.z + xv.w;
    float ss = xv.x*xv.x + xv.y*xv.y + xv.z*xv.z + xv.w*xv.w;
    __shared__ float rs[256], rss[256];
    rs[tid] = s; rss[tid] = ss;
    __syncthreads();
    for (int st = 128; st > 0; st >>= 1) {
        if (tid < st) { rs[tid] += rs[tid+st]; rss[tid] += rss[tid+st]; }
        __syncthreads();
    }
    float mean = rs[0] * (1.0f / EE);
    float var  = rss[0] * (1.0f / EE) - mean * mean;
    float rstd = rsqrtf(var + 1e-5f);
    const float4 gv = *(const float4*)(g + tid * 4);
    const float4 bv = *(const float4*)(bta + tid * 4);
    bf16x4 ov;
    ov[0] = (__bf16)((xv.x - mean) * rstd * gv.x + bv.x);
    ov[1] = (__bf16)((xv.y - mean) * rstd * gv.y + bv.y);
    ov[2] = (__bf16)((xv.z - mean) * rstd * gv.z + bv.z);
    ov[3] = (__bf16)((xv.w - mean) * rstd * gv.w + bv.w);
    *(bf16x4*)(out + (size_t)row * EE + tid * 4) = ov;
}

// ---------------- m97-style GEMM: C[M,N] = act(A[M,K] @ BT[N,K]^T + bias) --------
// TM x TN tile, BK=32, 4 waves (2x2). A, BT bf16, staged via global_load_lds w=16.
// LDS [row][32] (64B rows): lane l of wave w lands at row w*16+l/4, col (l&3)*8 —
// matches the wave-uniform-base + lane*16 DMA semantics.
template<int TM, int TN, bool GELU, bool RESID, typename CT>
__global__ __launch_bounds__(256) void gemm_bt_kernel(const __bf16* __restrict__ A,
                                                      const __bf16* __restrict__ BT,
                                                      const float* __restrict__ bias,
                                                      const float* resid, CT* C,
                                                      int M, int N, int K) {
    constexpr int MT = TM / 32;  // m-tiles per wave
    constexpr int NT = TN / 32;  // n-tiles per wave
    __shared__ __align__(16) __bf16 As[TM][32];
    __shared__ __align__(16) __bf16 Bs[TN][32];
    int tid = threadIdx.x, wave = tid >> 6, lane = tid & 63;
    int quad = lane >> 4, l16 = lane & 15;
    int wm = wave >> 1, wn = wave & 1;
    int m0 = blockIdx.y * TM, n0 = blockIdx.x * TN;

    f32x4 acc[MT][NT] = {};

    int srow = wave * 16 + (lane >> 2);   // staging row within a 64-row pass
    int scol = (lane & 3) * 8;            // staging col (elems)

    for (int kb = 0; kb < K; kb += 32) {
#pragma unroll
        for (int p = 0; p < TM / 64; p++) {
            const __bf16* g = A + (size_t)(m0 + p * 64 + srow) * K + kb + scol;
            __builtin_amdgcn_global_load_lds((AS1 const void*)g,
                                             (AS3 void*)&As[p * 64 + wave * 16][0], 16, 0, 0);
        }
#pragma unroll
        for (int p = 0; p < TN / 64; p++) {
            const __bf16* g = BT + (size_t)(n0 + p * 64 + srow) * K + kb + scol;
            __builtin_amdgcn_global_load_lds((AS1 const void*)g,
                                             (AS3 void*)&Bs[p * 64 + wave * 16][0], 16, 0, 0);
        }
        __syncthreads();
        bf16x8 af[MT], bfr[NT];
#pragma unroll
        for (int mt = 0; mt < MT; mt++)
            af[mt] = *(const bf16x8*)(&As[wm * (MT * 16) + mt * 16 + l16][quad * 8]);
#pragma unroll
        for (int nt = 0; nt < NT; nt++)
            bfr[nt] = *(const bf16x8*)(&Bs[wn * (NT * 16) + nt * 16 + l16][quad * 8]);
#pragma unroll
        for (int mt = 0; mt < MT; mt++)
#pragma unroll
            for (int nt = 0; nt < NT; nt++)
                acc[mt][nt] = __builtin_amdgcn_mfma_f32_16x16x32_bf16(af[mt], bfr[nt],
                                                                      acc[mt][nt], 0, 0, 0);
        __syncthreads();
    }

#pragma unroll
    for (int nt = 0; nt < NT; nt++) {
        int c = n0 + wn * (NT * 16) + nt * 16 + l16;
        float bv = bias[c];
#pragma unroll
        for (int mt = 0; mt < MT; mt++) {
#pragma unroll
            for (int r = 0; r < 4; r++) {
                int row = m0 + wm * (MT * 16) + mt * 16 + quad * 4 + r;
                float v = acc[mt][nt][r] + bv;
                if (GELU)  v = 0.5f * v * (1.0f + erff(v * 0.70710678118f));
                if (RESID) v += resid[(size_t)row * N + c];
                C[(size_t)row * N + c] = (CT)v;
            }
        }
    }
}

// ---------------- MFMA flash attention (unchanged from R4, verified) -------------
__global__ __launch_bounds__(256) void flash_attn_kernel(const __bf16* __restrict__ qkv,
                                                         __bf16* __restrict__ out) {
    int qt = (int)gridDim.x - 1 - (int)blockIdx.x;
    int h = blockIdx.y, b = blockIdx.z;
    int tid = threadIdx.x, wave = tid >> 6, lane = tid & 63;
    int quad = lane >> 4, l16 = lane & 15;
    int q0 = qt * 64;

    __shared__ __align__(16) __bf16 Ks[64][72];
    __shared__ __align__(16) __bf16 VTs[64][72];
    __shared__ __align__(16) __bf16 Ps[4][16][72];

    size_t base = (size_t)b * TT * (3 * EE);

    int qrow = q0 + wave * 16 + l16;
    const __bf16* qp = qkv + base + (size_t)qrow * (3 * EE) + h * HD;
    bf16x8 aq0 = *(const bf16x8*)(qp + quad * 8);
    bf16x8 aq1 = *(const bf16x8*)(qp + 32 + quad * 8);

    f32x4 oacc[4] = {};
    float m_i[4], l_i[4];
#pragma unroll
    for (int r = 0; r < 4; r++) { m_i[r] = -3.0e38f; l_i[r] = 0.0f; }
    int qg_base = q0 + wave * 16 + quad * 4;

    for (int kt = 0; kt <= qt; ++kt) {
        int k0 = kt * 64;
        int v = tid;
#pragma unroll
        for (int it = 0; it < 2; ++it, v += 256) {
            int row = v >> 3, col = (v & 7) * 8;
            const __bf16* kp = qkv + base + (size_t)(k0 + row) * (3 * EE) + EE + h * HD + col;
            const __bf16* vp = qkv + base + (size_t)(k0 + row) * (3 * EE) + 2 * EE + h * HD + col;
            *(bf16x8*)(&Ks[row][col]) = *(const bf16x8*)kp;
            bf16x8 vv = *(const bf16x8*)vp;
#pragma unroll
            for (int j = 0; j < 8; j++) VTs[col + j][row] = vv[j];
        }
        __syncthreads();

        f32x4 s[4] = {};
#pragma unroll
        for (int nt = 0; nt < 4; nt++) {
            bf16x8 bk0 = *(const bf16x8*)(&Ks[nt * 16 + l16][quad * 8]);
            bf16x8 bk1 = *(const bf16x8*)(&Ks[nt * 16 + l16][32 + quad * 8]);
            s[nt] = __builtin_amdgcn_mfma_f32_16x16x32_bf16(aq0, bk0, s[nt], 0, 0, 0);
            s[nt] = __builtin_amdgcn_mfma_f32_16x16x32_bf16(aq1, bk1, s[nt], 0, 0, 0);
        }

        bool maskt = (kt == qt);
        float rmax[4];
#pragma unroll
        for (int r = 0; r < 4; r++) rmax[r] = -3.0e38f;
#pragma unroll
        for (int nt = 0; nt < 4; nt++) {
            int key = k0 + nt * 16 + l16;
#pragma unroll
            for (int r = 0; r < 4; r++) {
                float sv = s[nt][r] * 0.125f;
                if (maskt && key > qg_base + r) sv = -3.0e38f;
                s[nt][r] = sv;
                rmax[r] = fmaxf(rmax[r], sv);
            }
        }
#pragma unroll
        for (int off = 1; off < 16; off <<= 1)
#pragma unroll
            for (int r = 0; r < 4; r++) rmax[r] = fmaxf(rmax[r], __shfl_xor(rmax[r], off));

        float alpha[4], rsum[4];
#pragma unroll
        for (int r = 0; r < 4; r++) {
            float mnew = fmaxf(m_i[r], rmax[r]);
            alpha[r] = __expf(m_i[r] - mnew);
            m_i[r] = mnew;
            rsum[r] = 0.0f;
        }
#pragma unroll
        for (int nt = 0; nt < 4; nt++) {
#pragma unroll
            for (int r = 0; r < 4; r++) {
                float p = __expf(s[nt][r] - m_i[r]);
                rsum[r] += p;
                Ps[wave][quad * 4 + r][nt * 16 + l16] = (__bf16)p;
            }
        }
#pragma unroll
        for (int off = 1; off < 16; off <<= 1)
#pragma unroll
            for (int r = 0; r < 4; r++) rsum[r] += __shfl_xor(rsum[r], off);
#pragma unroll
        for (int r = 0; r < 4; r++) {
            l_i[r] = l_i[r] * alpha[r] + rsum[r];
#pragma unroll
            for (int nt = 0; nt < 4; nt++) oacc[nt][r] *= alpha[r];
        }

#pragma unroll
        for (int half = 0; half < 2; half++) {
            bf16x8 ap = *(const bf16x8*)(&Ps[wave][l16][half * 32 + quad * 8]);
#pragma unroll
            for (int nt = 0; nt < 4; nt++) {
                bf16x8 bv = *(const bf16x8*)(&VTs[nt * 16 + l16][half * 32 + quad * 8]);
                oacc[nt] = __builtin_amdgcn_mfma_f32_16x16x32_bf16(ap, bv, oacc[nt], 0, 0, 0);
            }
        }
        __syncthreads();
    }

#pragma unroll
    for (int nt = 0; nt < 4; nt++) {
#pragma unroll
        for (int r = 0; r < 4; r++) {
            int qg = qg_base + r;
            out[((size_t)b * TT + qg) * EE + h * HD + nt * 16 + l16] =
                (__bf16)(oacc[nt][r] / l_i[r]);
        }
    }
}

extern "C" void kernel_launch(void* const* d_in, const int* in_sizes, int n_in,
                              void* d_out, int out_size, void* d_ws, size_t ws_size,
                              hipStream_t stream) {
    const float* x     = (const float*)d_in[0];
    const float* ln1g  = (const float*)d_in[1];
    const float* ln1b  = (const float*)d_in[2];
    const float* ln2g  = (const float*)d_in[3];
    const float* ln2b  = (const float*)d_in[4];
    const float* Wqkv  = (const float*)d_in[5];
    const float* bqkv  = (const float*)d_in[6];
    const float* Wo    = (const float*)d_in[7];
    const float* bo    = (const float*)d_in[8];
    const float* Wfc   = (const float*)d_in[9];
    const float* bfc   = (const float*)d_in[10];
    const float* Wproj = (const float*)d_in[11];
    const float* bproj = (const float*)d_in[12];
    float* out = (float*)d_out;

    const int M = 2 * TT;  // 4096 tokens

    // Workspace (bf16, 50.4 MB), lifetime-aliased:
    //   regQ [0, 16.8M):   qkv [4096x3072] (k2-3) then ff [4096x4096] (k6-7)
    //       tail [12.58M, 16.78M): WqkvT (3.15M) + WoT (1.05M) — dead before ff
    //   regS [16.8M, 21M): h1 -> atn -> h2 -> WprojT (converted after FC)
    //   WfcT [21M, 25.2M)
    //   x1 (fp32) lives in d_out
    __bf16* ws = (__bf16*)d_ws;
    __bf16* regQ   = ws;
    __bf16* regS   = ws + 16777216;
    __bf16* WfcT   = ws + 20971520;
    __bf16* qkv    = regQ;
    __bf16* ff     = regQ;
    __bf16* WqkvT  = regQ + 12582912;
    __bf16* WoT    = regQ + 15728640;
    __bf16* h1 = regS, *atn = regS, *h2 = regS;
    __bf16* WprojT = regS;
    float*  x1 = out;

    // weight conversions (fp32 [K][N] -> bf16 [N][K])
    convt_kernel<<<dim3(3 * EE / 32, EE / 32), 256, 0, stream>>>(Wqkv, WqkvT, EE, 3 * EE);
    convt_kernel<<<dim3(EE / 32, EE / 32), 256, 0, stream>>>(Wo, WoT, EE, EE);
    convt_kernel<<<dim3(4 * EE / 32, EE / 32), 256, 0, stream>>>(Wfc, WfcT, EE, 4 * EE);

    // LN1
    ln_kernel<<<M, 256, 0, stream>>>(x, ln1g, ln1b, h1);
    // QKV: [4096,1024] @ [1024,3072] -> qkv
    gemm_bt_kernel<128, 128, false, false, __bf16>
        <<<dim3(3 * EE / 128, M / 128), 256, 0, stream>>>(
        h1, WqkvT, bqkv, nullptr, qkv, M, 3 * EE, EE);
    // flash attention
    flash_attn_kernel<<<dim3(TT / 64, NH, 2), 256, 0, stream>>>(qkv, atn);
    // O-proj + residual(x) -> x1 (d_out)
    gemm_bt_kernel<128, 64, false, true, float>
        <<<dim3(EE / 64, M / 128), 256, 0, stream>>>(
        atn, WoT, bo, x, x1, M, EE, EE);
    // LN2
    ln_kernel<<<M, 256, 0, stream>>>(x1, ln2g, ln2b, h2);
    // FC + GELU -> ff (clobbers WqkvT/WoT — dead)
    gemm_bt_kernel<128, 128, true, false, __bf16>
        <<<dim3(4 * EE / 128, M / 128), 256, 0, stream>>>(
        h2, WfcT, bfc, nullptr, ff, M, 4 * EE, EE);
    // Wproj conversion into regS (h2 dead)
    convt_kernel<<<dim3(EE / 32, 4 * EE / 32), 256, 0, stream>>>(Wproj, WprojT, 4 * EE, EE);
    // proj + residual(x1) -> out (same-index RMW, safe)
    gemm_bt_kernel<128, 64, false, true, float>
        <<<dim3(EE / 64, M / 128), 256, 0, stream>>>(
        ff, WprojT, bproj, x1, out, M, EE, 4 * EE);
}

// Round 6
// 475.073 us; speedup vs baseline: 6.3812x; 1.0885x over previous
//
#include <hip/hip_runtime.h>
#include <hip/hip_bf16.h>

// Decoder block: B=2, T=2048, E=1024, H=16, D=64
// Inputs/outputs FP32; internals bf16 MFMA + fp32 accumulate.
// R6: flash attention gets (1) register prefetch of next K/V tile (hides global
// latency that caused 77% idle), (2) XOR-swizzled V^T LDS store (kills the
// 8-way bank conflicts: 2.0e7 cycles ~ 19% of the kernel). GEMMs unchanged.

#define TT 2048
#define EE 1024
#define NH 16
#define HD 64

#define AS1 __attribute__((address_space(1)))
#define AS3 __attribute__((address_space(3)))

using bf16x8 = __bf16 __attribute__((ext_vector_type(8)));
using bf16x4 = __bf16 __attribute__((ext_vector_type(4)));
using f32x4  = float __attribute__((ext_vector_type(4)));

// ---------------- fp32 [K][N] -> bf16 [N][K] tiled transpose-convert ------------
__global__ __launch_bounds__(256) void convt_kernel(const float* __restrict__ W,
                                                    __bf16* __restrict__ WT,
                                                    int K, int N) {
    __shared__ __bf16 t[32][33];
    int n0 = blockIdx.x * 32, k0 = blockIdx.y * 32;
    int tid = threadIdx.x;
    int r = tid >> 3, c4 = (tid & 7) * 4;
    float4 v = *(const float4*)(W + (size_t)(k0 + r) * N + n0 + c4);
    t[r][c4 + 0] = (__bf16)v.x; t[r][c4 + 1] = (__bf16)v.y;
    t[r][c4 + 2] = (__bf16)v.z; t[r][c4 + 3] = (__bf16)v.w;
    __syncthreads();
    bf16x4 o;
    o[0] = t[c4 + 0][r]; o[1] = t[c4 + 1][r];
    o[2] = t[c4 + 2][r]; o[3] = t[c4 + 3][r];
    *(bf16x4*)(WT + (size_t)(n0 + r) * K + k0 + c4) = o;
}

// ---------------- LayerNorm: fp32 in -> bf16 out. One block per row of 1024. ----
__global__ __launch_bounds__(256) void ln_kernel(const float* __restrict__ x,
                                                 const float* __restrict__ g,
                                                 const float* __restrict__ bta,
                                                 __bf16* __restrict__ out) {
    int row = blockIdx.x;
    int tid = threadIdx.x;
    const float4 xv = *(const float4*)(x + (size_t)row * EE + tid * 4);
    float s  = xv.x + xv.y + xv.z + xv.w;
    float ss = xv.x*xv.x + xv.y*xv.y + xv.z*xv.z + xv.w*xv.w;
    __shared__ float rs[256], rss[256];
    rs[tid] = s; rss[tid] = ss;
    __syncthreads();
    for (int st = 128; st > 0; st >>= 1) {
        if (tid < st) { rs[tid] += rs[tid+st]; rss[tid] += rss[tid+st]; }
        __syncthreads();
    }
    float mean = rs[0] * (1.0f / EE);
    float var  = rss[0] * (1.0f / EE) - mean * mean;
    float rstd = rsqrtf(var + 1e-5f);
    const float4 gv = *(const float4*)(g + tid * 4);
    const float4 bv = *(const float4*)(bta + tid * 4);
    bf16x4 ov;
    ov[0] = (__bf16)((xv.x - mean) * rstd * gv.x + bv.x);
    ov[1] = (__bf16)((xv.y - mean) * rstd * gv.y + bv.y);
    ov[2] = (__bf16)((xv.z - mean) * rstd * gv.z + bv.z);
    ov[3] = (__bf16)((xv.w - mean) * rstd * gv.w + bv.w);
    *(bf16x4*)(out + (size_t)row * EE + tid * 4) = ov;
}

// ---------------- m97-style GEMM (unchanged from R5, verified) -------------------
template<int TM, int TN, bool GELU, bool RESID, typename CT>
__global__ __launch_bounds__(256) void gemm_bt_kernel(const __bf16* __restrict__ A,
                                                      const __bf16* __restrict__ BT,
                                                      const float* __restrict__ bias,
                                                      const float* resid, CT* C,
                                                      int M, int N, int K) {
    constexpr int MT = TM / 32;
    constexpr int NT = TN / 32;
    __shared__ __align__(16) __bf16 As[TM][32];
    __shared__ __align__(16) __bf16 Bs[TN][32];
    int tid = threadIdx.x, wave = tid >> 6, lane = tid & 63;
    int quad = lane >> 4, l16 = lane & 15;
    int wm = wave >> 1, wn = wave & 1;
    int m0 = blockIdx.y * TM, n0 = blockIdx.x * TN;

    f32x4 acc[MT][NT] = {};

    int srow = wave * 16 + (lane >> 2);
    int scol = (lane & 3) * 8;

    for (int kb = 0; kb < K; kb += 32) {
#pragma unroll
        for (int p = 0; p < TM / 64; p++) {
            const __bf16* g = A + (size_t)(m0 + p * 64 + srow) * K + kb + scol;
            __builtin_amdgcn_global_load_lds((AS1 const void*)g,
                                             (AS3 void*)&As[p * 64 + wave * 16][0], 16, 0, 0);
        }
#pragma unroll
        for (int p = 0; p < TN / 64; p++) {
            const __bf16* g = BT + (size_t)(n0 + p * 64 + srow) * K + kb + scol;
            __builtin_amdgcn_global_load_lds((AS1 const void*)g,
                                             (AS3 void*)&Bs[p * 64 + wave * 16][0], 16, 0, 0);
        }
        __syncthreads();
        bf16x8 af[MT], bfr[NT];
#pragma unroll
        for (int mt = 0; mt < MT; mt++)
            af[mt] = *(const bf16x8*)(&As[wm * (MT * 16) + mt * 16 + l16][quad * 8]);
#pragma unroll
        for (int nt = 0; nt < NT; nt++)
            bfr[nt] = *(const bf16x8*)(&Bs[wn * (NT * 16) + nt * 16 + l16][quad * 8]);
#pragma unroll
        for (int mt = 0; mt < MT; mt++)
#pragma unroll
            for (int nt = 0; nt < NT; nt++)
                acc[mt][nt] = __builtin_amdgcn_mfma_f32_16x16x32_bf16(af[mt], bfr[nt],
                                                                      acc[mt][nt], 0, 0, 0);
        __syncthreads();
    }

#pragma unroll
    for (int nt = 0; nt < NT; nt++) {
        int c = n0 + wn * (NT * 16) + nt * 16 + l16;
        float bv = bias[c];
#pragma unroll
        for (int mt = 0; mt < MT; mt++) {
#pragma unroll
            for (int r = 0; r < 4; r++) {
                int row = m0 + wm * (MT * 16) + mt * 16 + quad * 4 + r;
                float v = acc[mt][nt][r] + bv;
                if (GELU)  v = 0.5f * v * (1.0f + erff(v * 0.70710678118f));
                if (RESID) v += resid[(size_t)row * N + c];
                C[(size_t)row * N + c] = (CT)v;
            }
        }
    }
}

// ---------------- MFMA flash attention (R6: prefetch + swizzled V^T) -------------
// V^T stored swizzled: V[key][d] lands at VTs[d][key ^ (((d>>3)&7)<<3)].
// Writes: per-thread d-block is constant -> swizzled key is loop-invariant;
// banks spread 4j+4(w^c)+r8/2 (conflict-free). Reads: ds_read_b128 at column
// block ((half*4+quad) ^ ((d>>3)&7))*8 — same values as R5's unswizzled read.
__global__ __launch_bounds__(256) void flash_attn_kernel(const __bf16* __restrict__ qkv,
                                                         __bf16* __restrict__ out) {
    int qt = (int)gridDim.x - 1 - (int)blockIdx.x;
    int h = blockIdx.y, b = blockIdx.z;
    int tid = threadIdx.x, wave = tid >> 6, lane = tid & 63;
    int quad = lane >> 4, l16 = lane & 15;
    int q0 = qt * 64;

    __shared__ __align__(16) __bf16 Ks[64][72];
    __shared__ __align__(16) __bf16 VTs[64][72];
    __shared__ __align__(16) __bf16 Ps[4][16][72];

    size_t base = (size_t)b * TT * (3 * EE);

    int qrow = q0 + wave * 16 + l16;
    const __bf16* qp = qkv + base + (size_t)qrow * (3 * EE) + h * HD;
    bf16x8 aq0 = *(const bf16x8*)(qp + quad * 8);
    bf16x8 aq1 = *(const bf16x8*)(qp + 32 + quad * 8);

    // staging geometry (per thread, loop-invariant)
    int srow = tid >> 3;            // 0..31 (it=0), +32 for it=1
    int scol = (tid & 7) * 8;       // d-block base; swizzle g = scol>>3
    int r1 = srow + 32;
    int kp0 = (srow & 7) | ((((srow >> 3) ^ (scol >> 3)) & 7) << 3);
    int kp1 = (r1 & 7)   | ((((r1 >> 3)   ^ (scol >> 3)) & 7) << 3);
    const __bf16* kbase = qkv + base + EE     + h * HD + scol;
    const __bf16* vbase = qkv + base + 2 * EE + h * HD + scol;

    f32x4 oacc[4] = {};
    float m_i[4], l_i[4];
#pragma unroll
    for (int r = 0; r < 4; r++) { m_i[r] = -3.0e38f; l_i[r] = 0.0f; }
    int qg_base = q0 + wave * 16 + quad * 4;

    // prefetch tile 0
    bf16x8 kr0 = *(const bf16x8*)(kbase + (size_t)srow * (3 * EE));
    bf16x8 kr1 = *(const bf16x8*)(kbase + (size_t)r1   * (3 * EE));
    bf16x8 vr0 = *(const bf16x8*)(vbase + (size_t)srow * (3 * EE));
    bf16x8 vr1 = *(const bf16x8*)(vbase + (size_t)r1   * (3 * EE));

    for (int kt = 0; kt <= qt; ++kt) {
        int k0 = kt * 64;
        // ---- stage prefetched regs into LDS ----
        *(bf16x8*)(&Ks[srow][scol]) = kr0;
        *(bf16x8*)(&Ks[r1][scol])   = kr1;
#pragma unroll
        for (int j = 0; j < 8; j++) VTs[scol + j][kp0] = vr0[j];
#pragma unroll
        for (int j = 0; j < 8; j++) VTs[scol + j][kp1] = vr1[j];
        __syncthreads();

        // ---- prefetch next tile (overlaps all compute below) ----
        if (kt < qt) {
            size_t off = (size_t)(k0 + 64) * (3 * EE);
            kr0 = *(const bf16x8*)(kbase + off + (size_t)srow * (3 * EE));
            kr1 = *(const bf16x8*)(kbase + off + (size_t)r1   * (3 * EE));
            vr0 = *(const bf16x8*)(vbase + off + (size_t)srow * (3 * EE));
            vr1 = *(const bf16x8*)(vbase + off + (size_t)r1   * (3 * EE));
        }

        // ---- S = Q K^T ----
        f32x4 s[4] = {};
#pragma unroll
        for (int nt = 0; nt < 4; nt++) {
            bf16x8 bk0 = *(const bf16x8*)(&Ks[nt * 16 + l16][quad * 8]);
            bf16x8 bk1 = *(const bf16x8*)(&Ks[nt * 16 + l16][32 + quad * 8]);
            s[nt] = __builtin_amdgcn_mfma_f32_16x16x32_bf16(aq0, bk0, s[nt], 0, 0, 0);
            s[nt] = __builtin_amdgcn_mfma_f32_16x16x32_bf16(aq1, bk1, s[nt], 0, 0, 0);
        }

        // ---- scale + causal mask + row max ----
        bool maskt = (kt == qt);
        float rmax[4];
#pragma unroll
        for (int r = 0; r < 4; r++) rmax[r] = -3.0e38f;
#pragma unroll
        for (int nt = 0; nt < 4; nt++) {
            int key = k0 + nt * 16 + l16;
#pragma unroll
            for (int r = 0; r < 4; r++) {
                float sv = s[nt][r] * 0.125f;
                if (maskt && key > qg_base + r) sv = -3.0e38f;
                s[nt][r] = sv;
                rmax[r] = fmaxf(rmax[r], sv);
            }
        }
#pragma unroll
        for (int off = 1; off < 16; off <<= 1)
#pragma unroll
            for (int r = 0; r < 4; r++) rmax[r] = fmaxf(rmax[r], __shfl_xor(rmax[r], off));

        // ---- online softmax update ----
        float alpha[4], rsum[4];
#pragma unroll
        for (int r = 0; r < 4; r++) {
            float mnew = fmaxf(m_i[r], rmax[r]);
            alpha[r] = __expf(m_i[r] - mnew);
            m_i[r] = mnew;
            rsum[r] = 0.0f;
        }
#pragma unroll
        for (int nt = 0; nt < 4; nt++) {
#pragma unroll
            for (int r = 0; r < 4; r++) {
                float p = __expf(s[nt][r] - m_i[r]);
                rsum[r] += p;
                Ps[wave][quad * 4 + r][nt * 16 + l16] = (__bf16)p;
            }
        }
#pragma unroll
        for (int off = 1; off < 16; off <<= 1)
#pragma unroll
            for (int r = 0; r < 4; r++) rsum[r] += __shfl_xor(rsum[r], off);
#pragma unroll
        for (int r = 0; r < 4; r++) {
            l_i[r] = l_i[r] * alpha[r] + rsum[r];
#pragma unroll
            for (int nt = 0; nt < 4; nt++) oacc[nt][r] *= alpha[r];
        }

        // ---- O += P V (V^T read with swizzled column block) ----
#pragma unroll
        for (int half = 0; half < 2; half++) {
            bf16x8 ap = *(const bf16x8*)(&Ps[wave][l16][half * 32 + quad * 8]);
#pragma unroll
            for (int nt = 0; nt < 4; nt++) {
                int g = (nt * 2 + (l16 >> 3)) & 7;
                int colr = (((half << 2) | quad) ^ g) << 3;
                bf16x8 bv = *(const bf16x8*)(&VTs[nt * 16 + l16][colr]);
                oacc[nt] = __builtin_amdgcn_mfma_f32_16x16x32_bf16(ap, bv, oacc[nt], 0, 0, 0);
            }
        }
        __syncthreads();
    }

#pragma unroll
    for (int nt = 0; nt < 4; nt++) {
#pragma unroll
        for (int r = 0; r < 4; r++) {
            int qg = qg_base + r;
            out[((size_t)b * TT + qg) * EE + h * HD + nt * 16 + l16] =
                (__bf16)(oacc[nt][r] / l_i[r]);
        }
    }
}

extern "C" void kernel_launch(void* const* d_in, const int* in_sizes, int n_in,
                              void* d_out, int out_size, void* d_ws, size_t ws_size,
                              hipStream_t stream) {
    const float* x     = (const float*)d_in[0];
    const float* ln1g  = (const float*)d_in[1];
    const float* ln1b  = (const float*)d_in[2];
    const float* ln2g  = (const float*)d_in[3];
    const float* ln2b  = (const float*)d_in[4];
    const float* Wqkv  = (const float*)d_in[5];
    const float* bqkv  = (const float*)d_in[6];
    const float* Wo    = (const float*)d_in[7];
    const float* bo    = (const float*)d_in[8];
    const float* Wfc   = (const float*)d_in[9];
    const float* bfc   = (const float*)d_in[10];
    const float* Wproj = (const float*)d_in[11];
    const float* bproj = (const float*)d_in[12];
    float* out = (float*)d_out;

    const int M = 2 * TT;  // 4096 tokens

    // Workspace (bf16, 50.4 MB), lifetime-aliased (see R5):
    __bf16* ws = (__bf16*)d_ws;
    __bf16* regQ   = ws;
    __bf16* regS   = ws + 16777216;
    __bf16* WfcT   = ws + 20971520;
    __bf16* qkv    = regQ;
    __bf16* ff     = regQ;
    __bf16* WqkvT  = regQ + 12582912;
    __bf16* WoT    = regQ + 15728640;
    __bf16* h1 = regS, *atn = regS, *h2 = regS;
    __bf16* WprojT = regS;
    float*  x1 = out;

    convt_kernel<<<dim3(3 * EE / 32, EE / 32), 256, 0, stream>>>(Wqkv, WqkvT, EE, 3 * EE);
    convt_kernel<<<dim3(EE / 32, EE / 32), 256, 0, stream>>>(Wo, WoT, EE, EE);
    convt_kernel<<<dim3(4 * EE / 32, EE / 32), 256, 0, stream>>>(Wfc, WfcT, EE, 4 * EE);

    ln_kernel<<<M, 256, 0, stream>>>(x, ln1g, ln1b, h1);
    gemm_bt_kernel<128, 128, false, false, __bf16>
        <<<dim3(3 * EE / 128, M / 128), 256, 0, stream>>>(
        h1, WqkvT, bqkv, nullptr, qkv, M, 3 * EE, EE);
    flash_attn_kernel<<<dim3(TT / 64, NH, 2), 256, 0, stream>>>(qkv, atn);
    gemm_bt_kernel<128, 64, false, true, float>
        <<<dim3(EE / 64, M / 128), 256, 0, stream>>>(
        atn, WoT, bo, x, x1, M, EE, EE);
    ln_kernel<<<M, 256, 0, stream>>>(x1, ln2g, ln2b, h2);
    gemm_bt_kernel<128, 128, true, false, __bf16>
        <<<dim3(4 * EE / 128, M / 128), 256, 0, stream>>>(
        h2, WfcT, bfc, nullptr, ff, M, 4 * EE, EE);
    convt_kernel<<<dim3(EE / 32, 4 * EE / 32), 256, 0, stream>>>(Wproj, WprojT, 4 * EE, EE);
    gemm_bt_kernel<128, 64, false, true, float>
        <<<dim3(EE / 64, M / 128), 256, 0, stream>>>(
        ff, WprojT, bproj, x1, out, M, EE, 4 * EE);
}

// Round 7
// 470.702 us; speedup vs baseline: 6.4404x; 1.0093x over previous
//
#include <hip/hip_runtime.h>
#include <hip/hip_bf16.h>

// Decoder block: B=2, T=2048, E=1024, H=16, D=64
// Inputs/outputs FP32; internals bf16 MFMA + fp32 accumulate.
// R7: flash attention K-tile 64 -> 128 (halves softmax bookkeeping + barriers
// per key), Ps aliased into Ks (LDS stays 35.8 KB -> 4 blocks/CU), full
// bank-swizzle on VTs (store f(row)=(row>>3)^(row&7)). GEMMs unchanged.

#define TT 2048
#define EE 1024
#define NH 16
#define HD 64

#define AS1 __attribute__((address_space(1)))
#define AS3 __attribute__((address_space(3)))

using bf16x8 = __bf16 __attribute__((ext_vector_type(8)));
using bf16x4 = __bf16 __attribute__((ext_vector_type(4)));
using f32x4  = float __attribute__((ext_vector_type(4)));

// ---------------- fp32 [K][N] -> bf16 [N][K] tiled transpose-convert ------------
__global__ __launch_bounds__(256) void convt_kernel(const float* __restrict__ W,
                                                    __bf16* __restrict__ WT,
                                                    int K, int N) {
    __shared__ __bf16 t[32][33];
    int n0 = blockIdx.x * 32, k0 = blockIdx.y * 32;
    int tid = threadIdx.x;
    int r = tid >> 3, c4 = (tid & 7) * 4;
    float4 v = *(const float4*)(W + (size_t)(k0 + r) * N + n0 + c4);
    t[r][c4 + 0] = (__bf16)v.x; t[r][c4 + 1] = (__bf16)v.y;
    t[r][c4 + 2] = (__bf16)v.z; t[r][c4 + 3] = (__bf16)v.w;
    __syncthreads();
    bf16x4 o;
    o[0] = t[c4 + 0][r]; o[1] = t[c4 + 1][r];
    o[2] = t[c4 + 2][r]; o[3] = t[c4 + 3][r];
    *(bf16x4*)(WT + (size_t)(n0 + r) * K + k0 + c4) = o;
}

// ---------------- LayerNorm: fp32 in -> bf16 out. One block per row of 1024. ----
__global__ __launch_bounds__(256) void ln_kernel(const float* __restrict__ x,
                                                 const float* __restrict__ g,
                                                 const float* __restrict__ bta,
                                                 __bf16* __restrict__ out) {
    int row = blockIdx.x;
    int tid = threadIdx.x;
    const float4 xv = *(const float4*)(x + (size_t)row * EE + tid * 4);
    float s  = xv.x + xv.y + xv.z + xv.w;
    float ss = xv.x*xv.x + xv.y*xv.y + xv.z*xv.z + xv.w*xv.w;
    __shared__ float rs[256], rss[256];
    rs[tid] = s; rss[tid] = ss;
    __syncthreads();
    for (int st = 128; st > 0; st >>= 1) {
        if (tid < st) { rs[tid] += rs[tid+st]; rss[tid] += rss[tid+st]; }
        __syncthreads();
    }
    float mean = rs[0] * (1.0f / EE);
    float var  = rss[0] * (1.0f / EE) - mean * mean;
    float rstd = rsqrtf(var + 1e-5f);
    const float4 gv = *(const float4*)(g + tid * 4);
    const float4 bv = *(const float4*)(bta + tid * 4);
    bf16x4 ov;
    ov[0] = (__bf16)((xv.x - mean) * rstd * gv.x + bv.x);
    ov[1] = (__bf16)((xv.y - mean) * rstd * gv.y + bv.y);
    ov[2] = (__bf16)((xv.z - mean) * rstd * gv.z + bv.z);
    ov[3] = (__bf16)((xv.w - mean) * rstd * gv.w + bv.w);
    *(bf16x4*)(out + (size_t)row * EE + tid * 4) = ov;
}

// ---------------- m97-style GEMM (unchanged from R5, verified) -------------------
template<int TM, int TN, bool GELU, bool RESID, typename CT>
__global__ __launch_bounds__(256) void gemm_bt_kernel(const __bf16* __restrict__ A,
                                                      const __bf16* __restrict__ BT,
                                                      const float* __restrict__ bias,
                                                      const float* resid, CT* C,
                                                      int M, int N, int K) {
    constexpr int MT = TM / 32;
    constexpr int NT = TN / 32;
    __shared__ __align__(16) __bf16 As[TM][32];
    __shared__ __align__(16) __bf16 Bs[TN][32];
    int tid = threadIdx.x, wave = tid >> 6, lane = tid & 63;
    int quad = lane >> 4, l16 = lane & 15;
    int wm = wave >> 1, wn = wave & 1;
    int m0 = blockIdx.y * TM, n0 = blockIdx.x * TN;

    f32x4 acc[MT][NT] = {};

    int srow = wave * 16 + (lane >> 2);
    int scol = (lane & 3) * 8;

    for (int kb = 0; kb < K; kb += 32) {
#pragma unroll
        for (int p = 0; p < TM / 64; p++) {
            const __bf16* g = A + (size_t)(m0 + p * 64 + srow) * K + kb + scol;
            __builtin_amdgcn_global_load_lds((AS1 const void*)g,
                                             (AS3 void*)&As[p * 64 + wave * 16][0], 16, 0, 0);
        }
#pragma unroll
        for (int p = 0; p < TN / 64; p++) {
            const __bf16* g = BT + (size_t)(n0 + p * 64 + srow) * K + kb + scol;
            __builtin_amdgcn_global_load_lds((AS1 const void*)g,
                                             (AS3 void*)&Bs[p * 64 + wave * 16][0], 16, 0, 0);
        }
        __syncthreads();
        bf16x8 af[MT], bfr[NT];
#pragma unroll
        for (int mt = 0; mt < MT; mt++)
            af[mt] = *(const bf16x8*)(&As[wm * (MT * 16) + mt * 16 + l16][quad * 8]);
#pragma unroll
        for (int nt = 0; nt < NT; nt++)
            bfr[nt] = *(const bf16x8*)(&Bs[wn * (NT * 16) + nt * 16 + l16][quad * 8]);
#pragma unroll
        for (int mt = 0; mt < MT; mt++)
#pragma unroll
            for (int nt = 0; nt < NT; nt++)
                acc[mt][nt] = __builtin_amdgcn_mfma_f32_16x16x32_bf16(af[mt], bfr[nt],
                                                                      acc[mt][nt], 0, 0, 0);
        __syncthreads();
    }

#pragma unroll
    for (int nt = 0; nt < NT; nt++) {
        int c = n0 + wn * (NT * 16) + nt * 16 + l16;
        float bv = bias[c];
#pragma unroll
        for (int mt = 0; mt < MT; mt++) {
#pragma unroll
            for (int r = 0; r < 4; r++) {
                int row = m0 + wm * (MT * 16) + mt * 16 + quad * 4 + r;
                float v = acc[mt][nt][r] + bv;
                if (GELU)  v = 0.5f * v * (1.0f + erff(v * 0.70710678118f));
                if (RESID) v += resid[(size_t)row * N + c];
                C[(size_t)row * N + c] = (CT)v;
            }
        }
    }
}

// ---------------- MFMA flash attention (R7: 128-key tiles, Ps in Ks) -------------
// Per iter (128 keys): stage -> B1 -> prefetch+QK -> B2 -> softmax+Ps(in Ks)+PV
// -> B3. VTs[d][key] swizzled: logical (key,d) at col ((kb ^ (d>>3) ^ (d&7))<<3)|k7.
__global__ __launch_bounds__(256) void flash_attn_kernel(const __bf16* __restrict__ qkv,
                                                         __bf16* __restrict__ out) {
    int qt = (int)gridDim.x - 1 - (int)blockIdx.x;  // big tiles first
    int h = blockIdx.y, b = blockIdx.z;
    int tid = threadIdx.x, wave = tid >> 6, lane = tid & 63;
    int quad = lane >> 4, l16 = lane & 15;
    int q0 = qt * 64;

    __shared__ __align__(16) __bf16 KsBuf[128 * 72];   // K tile; Ps alias per wave
    __shared__ __align__(16) __bf16 VTs[64][136];      // V^T, block-swizzled

    size_t base = (size_t)b * TT * (3 * EE);

    // Q A-fragments: A[m=l16][k=quad*8+j], two 32-wide k-halves of D=64
    int qrow = q0 + wave * 16 + l16;
    const __bf16* qp = qkv + base + (size_t)qrow * (3 * EE) + h * HD;
    bf16x8 aq0 = *(const bf16x8*)(qp + quad * 8);
    bf16x8 aq1 = *(const bf16x8*)(qp + 32 + quad * 8);

    // staging geometry
    int srow = tid >> 3;        // 0..31 (4 passes cover 128 rows)
    int g    = tid & 7;         // d-block index
    int scol = g * 8;
    const __bf16* kbase = qkv + base + EE     + h * HD + scol;
    const __bf16* vbase = qkv + base + 2 * EE + h * HD + scol;

    // Ps slice: wave's 32 Ks rows reinterpreted as [16 q][stride 136]
    __bf16* Psw = KsBuf + wave * (32 * 72);

    f32x4 oacc[4] = {};
    float m_i[4], l_i[4];
#pragma unroll
    for (int r = 0; r < 4; r++) { m_i[r] = -3.0e38f; l_i[r] = 0.0f; }
    int qg_base = q0 + wave * 16 + quad * 4;

    int nIter = (qt >> 1) + 1;

    // prefetch tile 0 (rows 0..127 always valid)
    bf16x8 kr[4], vr[4];
#pragma unroll
    for (int p = 0; p < 4; p++) {
        kr[p] = *(const bf16x8*)(kbase + (size_t)(32 * p + srow) * (3 * EE));
        vr[p] = *(const bf16x8*)(vbase + (size_t)(32 * p + srow) * (3 * EE));
    }

    for (int kt = 0; kt < nIter; ++kt) {
        int k0 = kt * 128;
        // ---- stage K and swizzled V^T from prefetch regs ----
#pragma unroll
        for (int p = 0; p < 4; p++) {
            int key = 32 * p + srow;
            *(bf16x8*)(&KsBuf[key * 72 + scol]) = kr[p];
            int kb = key >> 3, k7 = key & 7;
#pragma unroll
            for (int j = 0; j < 8; j++) {
                int pc = ((kb ^ (g ^ j)) << 3) | k7;
                VTs[scol + j][pc] = vr[p][j];
            }
        }
        __syncthreads();  // B1: staging visible

        // ---- prefetch next tile (hidden under QK/softmax/PV) ----
        if (kt < nIter - 1) {
            int kn = k0 + 128;
#pragma unroll
            for (int p = 0; p < 4; p++) {
                kr[p] = *(const bf16x8*)(kbase + (size_t)(kn + 32 * p + srow) * (3 * EE));
                vr[p] = *(const bf16x8*)(vbase + (size_t)(kn + 32 * p + srow) * (3 * EE));
            }
        }

        // ---- S = Q K^T over 128 keys ----
        f32x4 s[8];
#pragma unroll
        for (int nt = 0; nt < 8; nt++) {
            bf16x8 bk0 = *(const bf16x8*)(&KsBuf[(nt * 16 + l16) * 72 + quad * 8]);
            bf16x8 bk1 = *(const bf16x8*)(&KsBuf[(nt * 16 + l16) * 72 + 32 + quad * 8]);
            f32x4 z = {};
            z = __builtin_amdgcn_mfma_f32_16x16x32_bf16(aq0, bk0, z, 0, 0, 0);
            s[nt] = __builtin_amdgcn_mfma_f32_16x16x32_bf16(aq1, bk1, z, 0, 0, 0);
        }
        __syncthreads();  // B2: all waves done reading Ks -> Ps may overwrite

        // ---- scale + causal mask (remainder tile only) + row max ----
        bool maskt = (kt == nIter - 1);
        float rmax[4];
#pragma unroll
        for (int r = 0; r < 4; r++) rmax[r] = -3.0e38f;
#pragma unroll
        for (int nt = 0; nt < 8; nt++) {
            int key = k0 + nt * 16 + l16;
#pragma unroll
            for (int r = 0; r < 4; r++) {
                float sv = s[nt][r] * 0.125f;
                if (maskt && key > qg_base + r) sv = -3.0e38f;
                s[nt][r] = sv;
                rmax[r] = fmaxf(rmax[r], sv);
            }
        }
#pragma unroll
        for (int off = 1; off < 16; off <<= 1)
#pragma unroll
            for (int r = 0; r < 4; r++) rmax[r] = fmaxf(rmax[r], __shfl_xor(rmax[r], off));

        // ---- online softmax update (once per 128 keys) ----
        float alpha[4], rsum[4];
#pragma unroll
        for (int r = 0; r < 4; r++) {
            float mnew = fmaxf(m_i[r], rmax[r]);
            alpha[r] = __expf(m_i[r] - mnew);
            m_i[r] = mnew;
            rsum[r] = 0.0f;
        }
#pragma unroll
        for (int nt = 0; nt < 8; nt++) {
#pragma unroll
            for (int r = 0; r < 4; r++) {
                float p = __expf(s[nt][r] - m_i[r]);
                rsum[r] += p;
                Psw[(quad * 4 + r) * 136 + nt * 16 + l16] = (__bf16)p;
            }
        }
#pragma unroll
        for (int off = 1; off < 16; off <<= 1)
#pragma unroll
            for (int r = 0; r < 4; r++) rsum[r] += __shfl_xor(rsum[r], off);
#pragma unroll
        for (int r = 0; r < 4; r++) {
            l_i[r] = l_i[r] * alpha[r] + rsum[r];
#pragma unroll
            for (int dt = 0; dt < 4; dt++) oacc[dt][r] *= alpha[r];
        }

        // ---- O += P V over 128 keys ----
#pragma unroll
        for (int w = 0; w < 4; w++) {
            bf16x8 ap = *(const bf16x8*)(&Psw[l16 * 136 + w * 32 + quad * 8]);
#pragma unroll
            for (int dt = 0; dt < 4; dt++) {
                int fd = ((2 * dt + (l16 >> 3)) ^ l16) & 7;
                int cb = (4 * w + quad) ^ fd;
                bf16x8 bv = *(const bf16x8*)(&VTs[dt * 16 + l16][cb * 8]);
                oacc[dt] = __builtin_amdgcn_mfma_f32_16x16x32_bf16(ap, bv, oacc[dt], 0, 0, 0);
            }
        }
        __syncthreads();  // B3: VTs/Ps reads done before next staging
    }

    // ---- epilogue ----
#pragma unroll
    for (int dt = 0; dt < 4; dt++) {
#pragma unroll
        for (int r = 0; r < 4; r++) {
            int qg = qg_base + r;
            out[((size_t)b * TT + qg) * EE + h * HD + dt * 16 + l16] =
                (__bf16)(oacc[dt][r] / l_i[r]);
        }
    }
}

extern "C" void kernel_launch(void* const* d_in, const int* in_sizes, int n_in,
                              void* d_out, int out_size, void* d_ws, size_t ws_size,
                              hipStream_t stream) {
    const float* x     = (const float*)d_in[0];
    const float* ln1g  = (const float*)d_in[1];
    const float* ln1b  = (const float*)d_in[2];
    const float* ln2g  = (const float*)d_in[3];
    const float* ln2b  = (const float*)d_in[4];
    const float* Wqkv  = (const float*)d_in[5];
    const float* bqkv  = (const float*)d_in[6];
    const float* Wo    = (const float*)d_in[7];
    const float* bo    = (const float*)d_in[8];
    const float* Wfc   = (const float*)d_in[9];
    const float* bfc   = (const float*)d_in[10];
    const float* Wproj = (const float*)d_in[11];
    const float* bproj = (const float*)d_in[12];
    float* out = (float*)d_out;

    const int M = 2 * TT;  // 4096 tokens

    // Workspace (bf16, 50.4 MB), lifetime-aliased (see R5):
    __bf16* ws = (__bf16*)d_ws;
    __bf16* regQ   = ws;
    __bf16* regS   = ws + 16777216;
    __bf16* WfcT   = ws + 20971520;
    __bf16* qkv    = regQ;
    __bf16* ff     = regQ;
    __bf16* WqkvT  = regQ + 12582912;
    __bf16* WoT    = regQ + 15728640;
    __bf16* h1 = regS, *atn = regS, *h2 = regS;
    __bf16* WprojT = regS;
    float*  x1 = out;

    convt_kernel<<<dim3(3 * EE / 32, EE / 32), 256, 0, stream>>>(Wqkv, WqkvT, EE, 3 * EE);
    convt_kernel<<<dim3(EE / 32, EE / 32), 256, 0, stream>>>(Wo, WoT, EE, EE);
    convt_kernel<<<dim3(4 * EE / 32, EE / 32), 256, 0, stream>>>(Wfc, WfcT, EE, 4 * EE);

    ln_kernel<<<M, 256, 0, stream>>>(x, ln1g, ln1b, h1);
    gemm_bt_kernel<128, 128, false, false, __bf16>
        <<<dim3(3 * EE / 128, M / 128), 256, 0, stream>>>(
        h1, WqkvT, bqkv, nullptr, qkv, M, 3 * EE, EE);
    flash_attn_kernel<<<dim3(TT / 64, NH, 2), 256, 0, stream>>>(qkv, atn);
    gemm_bt_kernel<128, 64, false, true, float>
        <<<dim3(EE / 64, M / 128), 256, 0, stream>>>(
        atn, WoT, bo, x, x1, M, EE, EE);
    ln_kernel<<<M, 256, 0, stream>>>(x1, ln2g, ln2b, h2);
    gemm_bt_kernel<128, 128, true, false, __bf16>
        <<<dim3(4 * EE / 128, M / 128), 256, 0, stream>>>(
        h2, WfcT, bfc, nullptr, ff, M, 4 * EE, EE);
    convt_kernel<<<dim3(EE / 32, 4 * EE / 32), 256, 0, stream>>>(Wproj, WprojT, 4 * EE, EE);
    gemm_bt_kernel<128, 64, false, true, float>
        <<<dim3(EE / 64, M / 128), 256, 0, stream>>>(
        ff, WprojT, bproj, x1, out, M, EE, 4 * EE);
}